// Round 9
// baseline (186.788 us; speedup 1.0000x reference)
//
#include <hip/hip_runtime.h>

// B=64, S=512, D=256
#define NEG_INF (-4294967295.0f)

typedef _Float16 f16;
typedef _Float16 f16x8 __attribute__((ext_vector_type(8)));
typedef float f32x4 __attribute__((ext_vector_type(4)));

#define MFMA16(a,b,c) __builtin_amdgcn_mfma_f32_16x16x32_f16((a),(b),(c),0,0,0)

#if defined(__has_builtin)
#if __has_builtin(__builtin_amdgcn_global_load_lds)
#define HAS_GLD 1
#endif
#endif

// async 16B global->LDS; dest = lds_base + lane*16 (wave-uniform base)
__device__ __forceinline__ void stage16(const void* g, void* lds_base, int lane) {
#ifdef HAS_GLD
    __builtin_amdgcn_global_load_lds(
        (const __attribute__((address_space(1))) unsigned int*)g,
        (__attribute__((address_space(3))) unsigned int*)lds_base, 16, 0, 0);
#else
    ((f16x8*)lds_base)[lane] = *(const f16x8*)g;
#endif
}

// ---------------------------------------------------------------------------
// Fused setup: PEW = pe@W f32 (blocks 0..511, one s-row each), W^T f16
// (512..767), zero WG (768), zero out (769).
// ---------------------------------------------------------------------------
__global__ __launch_bounds__(256) void setup_kernel(const float* __restrict__ W,
                                                    f16* __restrict__ WT,
                                                    float* __restrict__ PEW,
                                                    float* __restrict__ WG,
                                                    float* __restrict__ out) {
    const int bid = blockIdx.x, t = threadIdx.x;
    if (bid < 512) {                       // PEW[s][e] = sum_d pe[s][d] * W[d][e]
        __shared__ float pr[256];
        const int s = bid;
        {
            int d = t;
            float x = (float)(d & ~1) * (1.f / 256.f);
            float rate = exp2f(x * -13.287712379549449f);   // 10000^-x
            float ang = (float)s * rate;
            pr[d] = (d & 1) ? cosf(ang) : sinf(ang);
        }
        __syncthreads();
        float acc = 0.f;
        #pragma unroll 8
        for (int d = 0; d < 256; ++d) acc = fmaf(pr[d], W[d * 256 + t], acc);
        PEW[s * 256 + t] = acc;
    } else if (bid < 768) {                // W^T[e][d] = W[d][e]
        int e = bid - 512;
        WT[(e << 8) + t] = (f16)W[(t << 8) + e];
    } else if (bid == 768) {               // zero w-accumulator (64*512 f32)
        #pragma unroll
        for (int i = 0; i < 128; ++i) WG[i * 256 + t] = 0.f;
    } else {                               // zero output (64*256 f32)
        #pragma unroll
        for (int i = 0; i < 64; ++i) out[i * 256 + t] = 0.f;
    }
}

// ---------------------------------------------------------------------------
// Projection: rows 0..32767=q, 32768..65535=k. out = relu(x@W + PEW)*0.25, f16.
// 1024 threads = 16 waves (4 row-grp x 4 col-grp), 64 rows x 256 cols/block,
// grid 1024 (2 blocks/CU). A staged as RAW f32 via async global_load_lds
// (no VGPR destinations -> latency decoupled from regfile); W^T f16 staged
// likewise. Both double-buffered, BK=32, XOR-swizzled to <=2-way conflicts.
// PEW bias added in epilogue (algebraic fold of the PE add).
// ---------------------------------------------------------------------------
__global__ __launch_bounds__(1024, 4) void proj_kernel(const float* __restrict__ q,
                                                       const float* __restrict__ k,
                                                       const f16* __restrict__ WT,
                                                       const float* __restrict__ PEW,
                                                       f16* __restrict__ outp) {
    // LDS bytes: A0 @0 (8K), A1 @8K, W0 @16K (16K), W1 @32K  -> 48 KB
    __shared__ __align__(16) char lds[49152];
    const int t = threadIdx.x, l = t & 63, wv = t >> 6, lr = l & 15, lg = l >> 4;
    const int wr = wv >> 2, wc = wv & 3;
    const int r0 = blockIdx.x * 64;
    const float* src = (r0 < 32768) ? q : k;
    const int rb = r0 & 32767;

    // waves 0..7 stage A (8x1KB: 8 rows x 128B each, chunk-of-16B XOR row&7);
    // waves 8..15 stage W^T [256e][32k] f16 (16x1KB: 16 e x 64B, chunk XOR (e>>1)&3)
    auto stageA = [&](int buf, int kc) {
        if (wv < 8) {
            int row = wv * 8 + (l >> 3);
            const float* s = src + (size_t)(rb + row) * 256 + kc * 32
                           + (((l & 7) ^ (l >> 3)) << 2);
            stage16(s, lds + buf * 8192 + wv * 1024, l);
        } else {
            int w8 = wv - 8;
            #pragma unroll
            for (int it = 0; it < 2; ++it) {
                int eb = w8 * 32 + it * 16;
                int e = eb + (l >> 2);
                const f16* s = WT + (e << 8) + kc * 32
                             + (((l & 3) ^ ((l >> 3) & 3)) << 3);
                stage16(s, lds + 16384 + buf * 16384 + (w8 * 2 + it) * 1024, l);
            }
        }
    };

    f32x4 acc[4] = {};
    stageA(0, 0);
    __syncthreads();

    #pragma unroll
    for (int kc = 0; kc < 8; ++kc) {
        const int cur = kc & 1;
        if (kc < 7) stageA(cur ^ 1, kc + 1);
        const float* Ab = (const float*)(lds + cur * 8192);
        const f16* Wb = (const f16*)(lds + 16384 + cur * 16384);
        int row_l = wr * 16 + lr;
        float4 fa = *(const float4*)&Ab[row_l * 32 + ((((lg * 2)     ) ^ (lr & 7)) << 2)];
        float4 fb = *(const float4*)&Ab[row_l * 32 + ((((lg * 2) | 1 ) ^ (lr & 7)) << 2)];
        f16x8 af;
        af[0] = (f16)fa.x; af[1] = (f16)fa.y; af[2] = (f16)fa.z; af[3] = (f16)fa.w;
        af[4] = (f16)fb.x; af[5] = (f16)fb.y; af[6] = (f16)fb.z; af[7] = (f16)fb.w;
        #pragma unroll
        for (int nt = 0; nt < 4; ++nt) {
            int e = wc * 64 + nt * 16 + lr;
            f16x8 bf = *(const f16x8*)&Wb[(e << 5) + ((lg ^ ((lr >> 1) & 3)) << 3)];
            acc[nt] = MFMA16(af, bf, acc[nt]);
        }
        if (kc < 7) __syncthreads();
    }
    __syncthreads();   // all buf reads done; LDS becomes the bounce arena

    // epilogue: +PEW bias, relu, *0.25 (folds 1/sqrt(D)); arena bounce ->
    // coalesced 16B stores. C-layout: row=lg*4+rg, col=lr (m89-verified).
    f16* arena = (f16*)lds;     // 32 KB: [64 rows][256 cols], chunk XOR row&7
    #pragma unroll
    for (int nt = 0; nt < 4; ++nt) {
        #pragma unroll
        for (int rg = 0; rg < 4; ++rg) {
            int row = wr * 16 + lg * 4 + rg;
            int col = wc * 64 + nt * 16 + lr;
            float v = acc[nt][rg] + PEW[(size_t)((r0 + row) & 511) * 256 + col];
            v = v > 0.f ? v * 0.25f : 0.f;
            arena[row * 256 + ((((col >> 3) ^ (row & 7)) << 3) | (col & 7))] = (f16)v;
        }
    }
    __syncthreads();
    #pragma unroll
    for (int i = 0; i < 2; ++i) {
        int idx = i * 1024 + t;
        int row = idx >> 5, ch = idx & 31;
        f16x8 v8 = *(const f16x8*)&arena[row * 256 + ((ch ^ (row & 7)) << 3)];
        *(f16x8*)(outp + (size_t)(r0 + row) * 256 + ch * 8) = v8;
    }
}

// ---------------------------------------------------------------------------
// Attention column-weights: w[b,k] = sum_q exp(S[q,k]) / l[q], l[q]=sum_k exp.
// (round-5/7-verified, unchanged)
// ---------------------------------------------------------------------------
__global__ __launch_bounds__(256) void attn_kernel(const f16* __restrict__ QP,
                                                   const f16* __restrict__ KP,
                                                   const int* __restrict__ mask,
                                                   float* __restrict__ wglob) {
    __shared__ __align__(16) f16 Ks[2][32 * 256];
    __shared__ float ws[4][512];
    const int t = threadIdx.x, l = t & 63, wv = t >> 6, lr = l & 15, lg = l >> 4;
    const int n = blockIdx.x, bb = n & 63, qt = n >> 6;
    const int q0 = qt * 64 + wv * 16;
    const int* maskb = mask + bb * 512;

    auto stageK = [&](int dst, int kt) {   // XOR-swizzled via pre-swizzled source
        #pragma unroll
        for (int it = 0; it < 4; ++it) {
            int r2 = wv * 8 + it * 2;
            int r = r2 + (l >> 5), c = l & 31;
            const f16* s = KP + (((size_t)(bb * 512 + kt * 32 + r)) << 8) + ((c ^ (r & 7)) << 3);
            stage16(s, &Ks[dst][r2 << 8], l);
        }
    };

    f16x8 qf[8];
    const f16* qrow = QP + (((size_t)(bb * 512 + q0 + lr)) << 8);
    #pragma unroll
    for (int kk = 0; kk < 8; ++kk) qf[kk] = *(const f16x8*)(qrow + kk * 32 + lg * 8);

    unsigned mb0 = 0, mb1 = 0;
    #pragma unroll
    for (int kt = 0; kt < 16; ++kt) {
        mb0 |= (maskb[kt * 32 + lr] ? 1u : 0u) << kt;
        mb1 |= (maskb[kt * 32 + 16 + lr] ? 1u : 0u) << kt;
    }

    float lacc[4] = {0.f, 0.f, 0.f, 0.f};
    f16 Pst[16][8];

    stageK(0, 0);
    __syncthreads();

    #pragma unroll
    for (int kt = 0; kt < 16; ++kt) {
        const int cur = kt & 1;
        if (kt < 15) stageK(cur ^ 1, kt + 1);
        f32x4 s0 = {}, s1 = {};
        #pragma unroll
        for (int kk = 0; kk < 8; ++kk) {
            int dk = kk * 32 + lg * 8;
            f16x8 b0 = *(const f16x8*)&Ks[cur][(lr << 8) + (dk ^ ((lr & 7) << 3))];
            f16x8 b1 = *(const f16x8*)&Ks[cur][((16 + lr) << 8) + (dk ^ ((lr & 7) << 3))];
            s0 = MFMA16(qf[kk], b0, s0);
            s1 = MFMA16(qf[kk], b1, s1);
        }
        #pragma unroll
        for (int rg = 0; rg < 4; ++rg) {
            float p0 = __expf(((mb0 >> kt) & 1) ? s0[rg] : NEG_INF);  // masked -> 0
            float p1 = __expf(((mb1 >> kt) & 1) ? s1[rg] : NEG_INF);
            f16 h0 = (f16)p0, h1 = (f16)p1;
            Pst[kt][rg] = h0;
            Pst[kt][4 + rg] = h1;
            lacc[rg] += (float)h0 + (float)h1;    // l from quantized p
        }
        if (kt < 15) __syncthreads();
    }

    #pragma unroll
    for (int rg = 0; rg < 4; ++rg) {
        float s = lacc[rg];
        s += __shfl_xor(s, 1); s += __shfl_xor(s, 2);
        s += __shfl_xor(s, 4); s += __shfl_xor(s, 8);
        lacc[rg] = s;
    }
    float rl[4];
    float bsum = 0.f;   // uniform fallback for all-masked batch (l==0)
    #pragma unroll
    for (int rg = 0; rg < 4; ++rg) {
        if (lacc[rg] > 0.f) { rl[rg] = 1.0f / lacc[rg]; }
        else                { rl[rg] = 0.f; bsum += 1.f / 512.f; }
    }

    #pragma unroll
    for (int kt = 0; kt < 16; ++kt) {
        float w0 = (float)Pst[kt][0] * rl[0] + (float)Pst[kt][1] * rl[1]
                 + (float)Pst[kt][2] * rl[2] + (float)Pst[kt][3] * rl[3] + bsum;
        float w1 = (float)Pst[kt][4] * rl[0] + (float)Pst[kt][5] * rl[1]
                 + (float)Pst[kt][6] * rl[2] + (float)Pst[kt][7] * rl[3] + bsum;
        w0 += __shfl_xor(w0, 16); w0 += __shfl_xor(w0, 32);
        w1 += __shfl_xor(w1, 16); w1 += __shfl_xor(w1, 32);
        if (lg == 0) {
            ws[wv][kt * 32 + lr] = w0;
            ws[wv][kt * 32 + 16 + lr] = w1;
        }
    }
    __syncthreads();
    #pragma unroll
    for (int i = 0; i < 2; ++i) {
        int kk = t + i * 256;
        float s = ws[0][kk] + ws[1][kk] + ws[2][kk] + ws[3][kk];
        atomicAdd(&wglob[bb * 512 + kk], s);
    }
}

// ---------------------------------------------------------------------------
// out[b,d] = (1/512) * sum_k w[b,k] V[b,k,d].  Grid 512: bb=n&63, 8 k-chunks.
// ---------------------------------------------------------------------------
__global__ __launch_bounds__(256) void wv_kernel(const float* __restrict__ wglob,
                                                 const float* __restrict__ V,
                                                 float* __restrict__ out) {
    const int n = blockIdx.x, bb = n & 63, ks = n >> 6;
    const int d = threadIdx.x;
    const float* wr = wglob + bb * 512 + ks * 64;
    const float* vb = V + ((((size_t)bb) * 512 + ks * 64) << 8) + d;
    float acc = 0.f;
    #pragma unroll 8
    for (int kk = 0; kk < 64; ++kk) acc = fmaf(wr[kk], vb[(size_t)kk << 8], acc);
    atomicAdd(&out[bb * 256 + d], acc * (1.f / 512.f));
}

// ---------------------------------------------------------------------------
extern "C" void kernel_launch(void* const* d_in, const int* in_sizes, int n_in,
                              void* d_out, int out_size, void* d_ws, size_t ws_size,
                              hipStream_t stream) {
    const float* q  = (const float*)d_in[0];
    const float* k  = (const float*)d_in[1];
    const float* v  = (const float*)d_in[2];
    const float* W  = (const float*)d_in[3];
    const int* mask = (const int*)d_in[4];

    char* ws = (char*)d_ws;
    f16*   QP  = (f16*)ws;                              // 16 MB
    f16*   KP  = (f16*)(ws + 16777216);                 // 16 MB
    f16*   WT  = (f16*)(ws + 33554432);                 // 128 KB
    float* PEW = (float*)(ws + 33685504);               // 512 KB
    float* WG  = (float*)(ws + 34209792);               // 128 KB

    setup_kernel<<<770, 256, 0, stream>>>(W, WT, PEW, WG, (float*)d_out);
    proj_kernel<<<1024, 1024, 0, stream>>>(q, k, WT, PEW, QP);
    attn_kernel<<<512, 256, 0, stream>>>(QP, KP, mask, WG);
    wv_kernel<<<512, 256, 0, stream>>>(WG, v, (float*)d_out);
}